// Round 3
// baseline (323.169 us; speedup 1.0000x reference)
//
#include <hip/hip_runtime.h>
#include <math.h>

#define THREADS 256
// fp32-vs-fp64 p error is <~1e-6 worst case; 1e-4 margin = 40x safety.
#define P_MARGIN 1e-4f

// Exact JAX threefry2x32 (20 rounds, key schedule every 4), key = (0, 42).
// Partitionable stream: bits[j] = o0 ^ o1 of threefry2x32(key, 0, j).
__device__ __forceinline__ void tf2x32(unsigned x0, unsigned x1,
                                       unsigned &o0, unsigned &o1) {
  const unsigned k0 = 0u;
  const unsigned k1 = 42u;
  const unsigned k2 = 0x1BD11BDAu ^ k0 ^ k1;
  x0 += k0; x1 += k1;
#define TF_R(r) { x0 += x1; x1 = (x1 << (r)) | (x1 >> (32 - (r))); x1 ^= x0; }
  TF_R(13) TF_R(15) TF_R(26) TF_R(6)
  x0 += k1; x1 += k2 + 1u;
  TF_R(17) TF_R(29) TF_R(16) TF_R(24)
  x0 += k2; x1 += k0 + 2u;
  TF_R(13) TF_R(15) TF_R(26) TF_R(6)
  x0 += k0; x1 += k1 + 3u;
  TF_R(17) TF_R(29) TF_R(16) TF_R(24)
  x0 += k1; x1 += k2 + 4u;
  TF_R(13) TF_R(15) TF_R(26) TF_R(6)
  x0 += k2; x1 += k0 + 5u;
#undef TF_R
  o0 = x0; o1 = x1;
}

// ---------------- Pass 1: fp32 fast path ----------------
// Weights transposed to [n][k] with k padded to x4 so every LDS weight read
// is a broadcast ds_read_b128. Rows whose bernoulli comparison is within
// P_MARGIN of the threshold get flagged for fp64 repair in pass 2.
__global__ __launch_bounds__(THREADS, 4)
void wtf_fast_kernel(const float* __restrict__ events,
                     const float* __restrict__ W1, const float* __restrict__ b1,
                     const float* __restrict__ g1, const float* __restrict__ be1,
                     const float* __restrict__ W2, const float* __restrict__ b2,
                     const float* __restrict__ g2, const float* __restrict__ be2,
                     const float* __restrict__ W3, const float* __restrict__ b3,
                     const float* __restrict__ g3, const float* __restrict__ be3,
                     const float* __restrict__ W4, const float* __restrict__ b4,
                     const float* __restrict__ W5, const float* __restrict__ b5,
                     float* __restrict__ out_chosen,
                     float* __restrict__ out_logp,
                     unsigned* __restrict__ flagbits,
                     int B) {
  __shared__ float4 sW1t[50 * 8];   // [n][k/4], k=32
  __shared__ float4 sW2t[30 * 13];  // k: 50 -> pad 52
  __shared__ float4 sW3t[20 * 8];   // k: 30 -> pad 32
  __shared__ float4 sW4t[15 * 5];   // k=20
  __shared__ float4 sW5t[8 * 4];    // k: 15 -> pad 16
  __shared__ float sb1[50], ss1[50], sbe1[50];
  __shared__ float sb2[30], ss2[30], sbe2[30];
  __shared__ float sb3[20], ss3[20], sbe3[20];
  __shared__ float sb4[15], sb5[8];

  const int t = threadIdx.x;
  {
    float* w = (float*)sW1t;
    for (int i = t; i < 1600; i += THREADS) { int n = i >> 5, k = i & 31; w[i] = W1[k * 50 + n]; }
    w = (float*)sW2t;
    for (int i = t; i < 1560; i += THREADS) { int n = i / 52, k = i - n * 52; w[i] = (k < 50) ? W2[k * 30 + n] : 0.f; }
    w = (float*)sW3t;
    for (int i = t; i < 640; i += THREADS)  { int n = i >> 5, k = i & 31; w[i] = (k < 30) ? W3[k * 20 + n] : 0.f; }
    w = (float*)sW4t;
    for (int i = t; i < 300; i += THREADS)  { int n = i / 20, k = i - n * 20; w[i] = W4[k * 15 + n]; }
    w = (float*)sW5t;
    for (int i = t; i < 128; i += THREADS)  { int n = i >> 4, k = i & 15; w[i] = (k < 15) ? W5[k * 8 + n] : 0.f; }
    const float rden = (float)(1.0 / sqrt(1.0 + 1e-5));
    if (t < 50) { sb1[t] = b1[t]; ss1[t] = g1[t] * rden; sbe1[t] = be1[t]; }
    if (t < 30) { sb2[t] = b2[t]; ss2[t] = g2[t] * rden; sbe2[t] = be2[t]; }
    if (t < 20) { sb3[t] = b3[t]; ss3[t] = g3[t] * rden; sbe3[t] = be3[t]; }
    if (t < 15) { sb4[t] = b4[t]; }
    if (t < 8)  { sb5[t] = b5[t]; }
  }
  __syncthreads();

  const int b = blockIdx.x * THREADS + t;
  if (b >= B) return;

  float x[32];
  const float4* ev4 = reinterpret_cast<const float4*>(events) + (size_t)b * 8;
#pragma unroll
  for (int q = 0; q < 8; ++q) {
    float4 v = ev4[q];
    x[4 * q + 0] = v.x; x[4 * q + 1] = v.y; x[4 * q + 2] = v.z; x[4 * q + 3] = v.w;
  }

  // layer 1: 32 -> 50
  float a1[52]; a1[50] = 0.f; a1[51] = 0.f;
#pragma unroll
  for (int n = 0; n < 50; ++n) {
    const float4* wr = &sW1t[n * 8];
    float c0 = 0.f, c1 = 0.f, c2 = 0.f, c3 = 0.f;
#pragma unroll
    for (int q = 0; q < 8; ++q) {
      float4 wv = wr[q];
      c0 = fmaf(x[4 * q + 0], wv.x, c0); c1 = fmaf(x[4 * q + 1], wv.y, c1);
      c2 = fmaf(x[4 * q + 2], wv.z, c2); c3 = fmaf(x[4 * q + 3], wv.w, c3);
    }
    float s = (c0 + c1) + (c2 + c3);
    s += sb1[n];
    s = fmaf(s, ss1[n], sbe1[n]);
    a1[n] = fmaxf(s, 0.f);
  }

  // layer 2: 50 -> 30
  float a2[32]; a2[30] = 0.f; a2[31] = 0.f;
#pragma unroll
  for (int n = 0; n < 30; ++n) {
    const float4* wr = &sW2t[n * 13];
    float c0 = 0.f, c1 = 0.f, c2 = 0.f, c3 = 0.f;
#pragma unroll
    for (int q = 0; q < 13; ++q) {
      float4 wv = wr[q];
      c0 = fmaf(a1[4 * q + 0], wv.x, c0); c1 = fmaf(a1[4 * q + 1], wv.y, c1);
      c2 = fmaf(a1[4 * q + 2], wv.z, c2); c3 = fmaf(a1[4 * q + 3], wv.w, c3);
    }
    float s = (c0 + c1) + (c2 + c3);
    s += sb2[n];
    s = fmaf(s, ss2[n], sbe2[n]);
    a2[n] = fmaxf(s, 0.f);
  }

  // layer 3: 30 -> 20
  float a3[20];
#pragma unroll
  for (int n = 0; n < 20; ++n) {
    const float4* wr = &sW3t[n * 8];
    float c0 = 0.f, c1 = 0.f, c2 = 0.f, c3 = 0.f;
#pragma unroll
    for (int q = 0; q < 8; ++q) {
      float4 wv = wr[q];
      c0 = fmaf(a2[4 * q + 0], wv.x, c0); c1 = fmaf(a2[4 * q + 1], wv.y, c1);
      c2 = fmaf(a2[4 * q + 2], wv.z, c2); c3 = fmaf(a2[4 * q + 3], wv.w, c3);
    }
    float s = (c0 + c1) + (c2 + c3);
    s += sb3[n];
    s = fmaf(s, ss3[n], sbe3[n]);
    a3[n] = fmaxf(s, 0.f);
  }

  // layer 4: 20 -> 15 (no BN)
  float a4[16]; a4[15] = 0.f;
#pragma unroll
  for (int n = 0; n < 15; ++n) {
    const float4* wr = &sW4t[n * 5];
    float c0 = 0.f, c1 = 0.f, c2 = 0.f, c3 = 0.f;
#pragma unroll
    for (int q = 0; q < 5; ++q) {
      float4 wv = wr[q];
      c0 = fmaf(a3[4 * q + 0], wv.x, c0); c1 = fmaf(a3[4 * q + 1], wv.y, c1);
      c2 = fmaf(a3[4 * q + 2], wv.z, c2); c3 = fmaf(a3[4 * q + 3], wv.w, c3);
    }
    float s = (c0 + c1) + (c2 + c3);
    s += sb4[n];
    a4[n] = fmaxf(s, 0.f);
  }

  // layer 5: 15 -> 8, sigmoid
  float p[8];
#pragma unroll
  for (int n = 0; n < 8; ++n) {
    const float4* wr = &sW5t[n * 4];
    float c0 = 0.f, c1 = 0.f, c2 = 0.f, c3 = 0.f;
#pragma unroll
    for (int q = 0; q < 4; ++q) {
      float4 wv = wr[q];
      c0 = fmaf(a4[4 * q + 0], wv.x, c0); c1 = fmaf(a4[4 * q + 1], wv.y, c1);
      c2 = fmaf(a4[4 * q + 2], wv.z, c2); c3 = fmaf(a4[4 * q + 3], wv.w, c3);
    }
    float s = (c0 + c1) + (c2 + c3) + sb5[n];
    p[n] = 1.f / (1.f + expf(-s));
  }

  // bernoulli(1-p) via partitionable threefry + margin flag
  bool need = false;
  float prod = 1.f;
  float ch[8];
#pragma unroll
  for (int w = 0; w < 8; ++w) {
    unsigned j = 8u * (unsigned)b + (unsigned)w, o0, o1;
    tf2x32(0u, j, o0, o1);
    unsigned bits = o0 ^ o1;
    float u = __uint_as_float(0x3F800000u | (bits >> 9)) - 1.f;
    float thr = 1.f - p[w];
    bool choice = u < thr;
    need = need || (fabsf(u - thr) < P_MARGIN);
    ch[w] = choice ? 0.f : 1.f;
    prod *= choice ? thr : p[w];
  }
  if (need) atomicOr(&flagbits[b >> 5], 1u << (b & 31));

  float4* oc = reinterpret_cast<float4*>(out_chosen) + (size_t)b * 2;
  oc[0] = make_float4(ch[0], ch[1], ch[2], ch[3]);
  oc[1] = make_float4(ch[4], ch[5], ch[6], ch[7]);
  out_logp[b] = logf(prod);
}

// ---------------- Pass 2: fp64 repair for flagged rows ----------------
// Exactly the R2 fp64 computation (which passed validation), gated per row.
__global__ __launch_bounds__(THREADS, 2)
void wtf_fix_kernel(const float* __restrict__ events,
                    const float* __restrict__ W1, const float* __restrict__ b1,
                    const float* __restrict__ g1, const float* __restrict__ be1,
                    const float* __restrict__ W2, const float* __restrict__ b2,
                    const float* __restrict__ g2, const float* __restrict__ be2,
                    const float* __restrict__ W3, const float* __restrict__ b3,
                    const float* __restrict__ g3, const float* __restrict__ be3,
                    const float* __restrict__ W4, const float* __restrict__ b4,
                    const float* __restrict__ W5, const float* __restrict__ b5,
                    float* __restrict__ out_chosen,
                    float* __restrict__ out_logp,
                    const unsigned* __restrict__ flagbits,
                    int B) {
  __shared__ int s_any;
  const int t = threadIdx.x;
  const int b = blockIdx.x * THREADS + t;
  if (t == 0) s_any = 0;
  __syncthreads();
  const unsigned f = (b < B) ? ((flagbits[b >> 5] >> (b & 31)) & 1u) : 0u;
  if (f) atomicOr(&s_any, 1);
  __syncthreads();
  if (!s_any) return;  // block-uniform early out — vast majority of blocks

  __shared__ double sW1[32 * 50]; __shared__ double sb1[50];
  __shared__ double ss1[50];      __shared__ double sbe1[50];
  __shared__ double sW2[50 * 30]; __shared__ double sb2[30];
  __shared__ double ss2[30];      __shared__ double sbe2[30];
  __shared__ double sW3[30 * 20]; __shared__ double sb3[20];
  __shared__ double ss3[20];      __shared__ double sbe3[20];
  __shared__ double sW4[20 * 15]; __shared__ double sb4[15];
  __shared__ double sW5[15 * 8];  __shared__ double sb5[8];

  const double denom = sqrt(1.0 + 1e-5);
  for (int i = t; i < 1600; i += THREADS) sW1[i] = (double)W1[i];
  for (int i = t; i < 1500; i += THREADS) sW2[i] = (double)W2[i];
  for (int i = t; i < 600;  i += THREADS) sW3[i] = (double)W3[i];
  for (int i = t; i < 300;  i += THREADS) sW4[i] = (double)W4[i];
  for (int i = t; i < 120;  i += THREADS) sW5[i] = (double)W5[i];
  if (t < 50) { sb1[t] = (double)b1[t]; ss1[t] = (double)g1[t] / denom; sbe1[t] = (double)be1[t]; }
  if (t < 30) { sb2[t] = (double)b2[t]; ss2[t] = (double)g2[t] / denom; sbe2[t] = (double)be2[t]; }
  if (t < 20) { sb3[t] = (double)b3[t]; ss3[t] = (double)g3[t] / denom; sbe3[t] = (double)be3[t]; }
  if (t < 15) { sb4[t] = (double)b4[t]; }
  if (t < 8)  { sb5[t] = (double)b5[t]; }
  __syncthreads();

  if (!f || b >= B) return;

  double x[32];
  const float4* ev4 = reinterpret_cast<const float4*>(events) + (size_t)b * 8;
#pragma unroll
  for (int q = 0; q < 8; ++q) {
    float4 v = ev4[q];
    x[4 * q + 0] = (double)v.x; x[4 * q + 1] = (double)v.y;
    x[4 * q + 2] = (double)v.z; x[4 * q + 3] = (double)v.w;
  }

  double a1[50];
#pragma unroll
  for (int n = 0; n < 50; ++n) {
    double acc = 0.0;
#pragma unroll
    for (int k = 0; k < 32; ++k) acc = fma(x[k], sW1[k * 50 + n], acc);
    acc += sb1[n];
    acc = acc * ss1[n] + sbe1[n];
    a1[n] = acc > 0.0 ? acc : 0.0;
  }
  double a2[30];
#pragma unroll
  for (int n = 0; n < 30; ++n) {
    double acc = 0.0;
#pragma unroll
    for (int k = 0; k < 50; ++k) acc = fma(a1[k], sW2[k * 30 + n], acc);
    acc += sb2[n];
    acc = acc * ss2[n] + sbe2[n];
    a2[n] = acc > 0.0 ? acc : 0.0;
  }
  double a3[20];
#pragma unroll
  for (int n = 0; n < 20; ++n) {
    double acc = 0.0;
#pragma unroll
    for (int k = 0; k < 30; ++k) acc = fma(a2[k], sW3[k * 20 + n], acc);
    acc += sb3[n];
    acc = acc * ss3[n] + sbe3[n];
    a3[n] = acc > 0.0 ? acc : 0.0;
  }
  double a4[15];
#pragma unroll
  for (int n = 0; n < 15; ++n) {
    double acc = 0.0;
#pragma unroll
    for (int k = 0; k < 20; ++k) acc = fma(a3[k], sW4[k * 15 + n], acc);
    acc += sb4[n];
    a4[n] = acc > 0.0 ? acc : 0.0;
  }
  double p[8];
#pragma unroll
  for (int n = 0; n < 8; ++n) {
    double acc = 0.0;
#pragma unroll
    for (int k = 0; k < 15; ++k) acc = fma(a4[k], sW5[k * 8 + n], acc);
    acc += sb5[n];
    p[n] = 1.0 / (1.0 + exp(-acc));
  }

  double prod = 1.0;
  float ch[8];
#pragma unroll
  for (int w = 0; w < 8; ++w) {
    unsigned j = 8u * (unsigned)b + (unsigned)w, o0, o1;
    tf2x32(0u, j, o0, o1);
    unsigned bits = o0 ^ o1;
    float u = __uint_as_float(0x3F800000u | (bits >> 9)) - 1.f;
    double thr = 1.0 - p[w];
    bool choice = ((double)u < thr);
    ch[w] = choice ? 0.f : 1.f;
    prod *= choice ? thr : p[w];
  }
  float4* oc = reinterpret_cast<float4*>(out_chosen) + (size_t)b * 2;
  oc[0] = make_float4(ch[0], ch[1], ch[2], ch[3]);
  oc[1] = make_float4(ch[4], ch[5], ch[6], ch[7]);
  out_logp[b] = (float)log(prod);
}

extern "C" void kernel_launch(void* const* d_in, const int* in_sizes, int n_in,
                              void* d_out, int out_size, void* d_ws, size_t ws_size,
                              hipStream_t stream) {
  const float* events = (const float*)d_in[0];
  const float* W1  = (const float*)d_in[1];
  const float* b1  = (const float*)d_in[2];
  const float* g1  = (const float*)d_in[3];
  const float* be1 = (const float*)d_in[4];
  const float* W2  = (const float*)d_in[5];
  const float* b2  = (const float*)d_in[6];
  const float* g2  = (const float*)d_in[7];
  const float* be2 = (const float*)d_in[8];
  const float* W3  = (const float*)d_in[9];
  const float* b3  = (const float*)d_in[10];
  const float* g3  = (const float*)d_in[11];
  const float* be3 = (const float*)d_in[12];
  const float* W4  = (const float*)d_in[13];
  const float* b4  = (const float*)d_in[14];
  const float* W5  = (const float*)d_in[15];
  const float* b5  = (const float*)d_in[16];

  const int B = in_sizes[0] / 32;  // 524288
  float* out = (float*)d_out;
  float* out_chosen = out;                   // (B, 8)
  float* out_logp   = out + (size_t)B * 8;   // (B,)
  unsigned* flagbits = (unsigned*)d_ws;      // 1 bit per row
  const size_t flag_bytes = (size_t)((B + 31) / 32) * sizeof(unsigned);

  hipMemsetAsync(d_ws, 0, flag_bytes, stream);

  const int blocks = (B + THREADS - 1) / THREADS;
  hipLaunchKernelGGL(wtf_fast_kernel, dim3(blocks), dim3(THREADS), 0, stream,
                     events, W1, b1, g1, be1, W2, b2, g2, be2,
                     W3, b3, g3, be3, W4, b4, W5, b5,
                     out_chosen, out_logp, flagbits, B);
  hipLaunchKernelGGL(wtf_fix_kernel, dim3(blocks), dim3(THREADS), 0, stream,
                     events, W1, b1, g1, be1, W2, b2, g2, be2,
                     W3, b3, g3, be3, W4, b4, W5, b5,
                     out_chosen, out_logp, flagbits, B);
}

// Round 4
// 256.651 us; speedup vs baseline: 1.2592x; 1.2592x over previous
//
#include <hip/hip_runtime.h>
#include <math.h>

#define THREADS 256
// fp32-vs-fp64 p error is <~2.5e-6 worst case; 1e-4 margin = 40x safety.
#define P_MARGIN 1e-4f

// Exact JAX threefry2x32 (20 rounds, key schedule every 4), key = (0, 42).
// Partitionable stream: bits[j] = o0 ^ o1 of threefry2x32(key, 0, j).
__device__ __forceinline__ void tf2x32(unsigned x0, unsigned x1,
                                       unsigned &o0, unsigned &o1) {
  const unsigned k0 = 0u;
  const unsigned k1 = 42u;
  const unsigned k2 = 0x1BD11BDAu ^ k0 ^ k1;
  x0 += k0; x1 += k1;
#define TF_R(r) { x0 += x1; x1 = (x1 << (r)) | (x1 >> (32 - (r))); x1 ^= x0; }
  TF_R(13) TF_R(15) TF_R(26) TF_R(6)
  x0 += k1; x1 += k2 + 1u;
  TF_R(17) TF_R(29) TF_R(16) TF_R(24)
  x0 += k2; x1 += k0 + 2u;
  TF_R(13) TF_R(15) TF_R(26) TF_R(6)
  x0 += k0; x1 += k1 + 3u;
  TF_R(17) TF_R(29) TF_R(16) TF_R(24)
  x0 += k1; x1 += k2 + 4u;
  TF_R(13) TF_R(15) TF_R(26) TF_R(6)
  x0 += k2; x1 += k0 + 5u;
#undef TF_R
  o0 = x0; o1 = x1;
}

// ---------------- Pass 1: fp32 fast path ----------------
// Weights transposed to [n][k] with k padded to x4 so every LDS weight read
// is a broadcast ds_read_b128. Rows whose bernoulli comparison is within
// P_MARGIN of the threshold get appended to a repair list for pass 2.
__global__ __launch_bounds__(THREADS, 4)
void wtf_fast_kernel(const float* __restrict__ events,
                     const float* __restrict__ W1, const float* __restrict__ b1,
                     const float* __restrict__ g1, const float* __restrict__ be1,
                     const float* __restrict__ W2, const float* __restrict__ b2,
                     const float* __restrict__ g2, const float* __restrict__ be2,
                     const float* __restrict__ W3, const float* __restrict__ b3,
                     const float* __restrict__ g3, const float* __restrict__ be3,
                     const float* __restrict__ W4, const float* __restrict__ b4,
                     const float* __restrict__ W5, const float* __restrict__ b5,
                     float* __restrict__ out_chosen,
                     float* __restrict__ out_logp,
                     unsigned* __restrict__ fixlist,  // [0]=count, rows at [1+i]
                     unsigned fixcap,
                     int B) {
  __shared__ float4 sW1t[50 * 8];   // [n][k/4], k=32
  __shared__ float4 sW2t[30 * 13];  // k: 50 -> pad 52
  __shared__ float4 sW3t[20 * 8];   // k: 30 -> pad 32
  __shared__ float4 sW4t[15 * 5];   // k=20
  __shared__ float4 sW5t[8 * 4];    // k: 15 -> pad 16
  __shared__ float sb1[50], ss1[50], sbe1[50];
  __shared__ float sb2[30], ss2[30], sbe2[30];
  __shared__ float sb3[20], ss3[20], sbe3[20];
  __shared__ float sb4[15], sb5[8];

  const int t = threadIdx.x;
  {
    float* w = (float*)sW1t;
    for (int i = t; i < 1600; i += THREADS) { int n = i >> 5, k = i & 31; w[i] = W1[k * 50 + n]; }
    w = (float*)sW2t;
    for (int i = t; i < 1560; i += THREADS) { int n = i / 52, k = i - n * 52; w[i] = (k < 50) ? W2[k * 30 + n] : 0.f; }
    w = (float*)sW3t;
    for (int i = t; i < 640; i += THREADS)  { int n = i >> 5, k = i & 31; w[i] = (k < 30) ? W3[k * 20 + n] : 0.f; }
    w = (float*)sW4t;
    for (int i = t; i < 300; i += THREADS)  { int n = i / 20, k = i - n * 20; w[i] = W4[k * 15 + n]; }
    w = (float*)sW5t;
    for (int i = t; i < 128; i += THREADS)  { int n = i >> 4, k = i & 15; w[i] = (k < 15) ? W5[k * 8 + n] : 0.f; }
    const float rden = (float)(1.0 / sqrt(1.0 + 1e-5));
    if (t < 50) { sb1[t] = b1[t]; ss1[t] = g1[t] * rden; sbe1[t] = be1[t]; }
    if (t < 30) { sb2[t] = b2[t]; ss2[t] = g2[t] * rden; sbe2[t] = be2[t]; }
    if (t < 20) { sb3[t] = b3[t]; ss3[t] = g3[t] * rden; sbe3[t] = be3[t]; }
    if (t < 15) { sb4[t] = b4[t]; }
    if (t < 8)  { sb5[t] = b5[t]; }
  }
  __syncthreads();

  const int b = blockIdx.x * THREADS + t;
  if (b >= B) return;

  float x[32];
  const float4* ev4 = reinterpret_cast<const float4*>(events) + (size_t)b * 8;
#pragma unroll
  for (int q = 0; q < 8; ++q) {
    float4 v = ev4[q];
    x[4 * q + 0] = v.x; x[4 * q + 1] = v.y; x[4 * q + 2] = v.z; x[4 * q + 3] = v.w;
  }

  // layer 1: 32 -> 50
  float a1[52]; a1[50] = 0.f; a1[51] = 0.f;
#pragma unroll
  for (int n = 0; n < 50; ++n) {
    const float4* wr = &sW1t[n * 8];
    float c0 = 0.f, c1 = 0.f, c2 = 0.f, c3 = 0.f;
#pragma unroll
    for (int q = 0; q < 8; ++q) {
      float4 wv = wr[q];
      c0 = fmaf(x[4 * q + 0], wv.x, c0); c1 = fmaf(x[4 * q + 1], wv.y, c1);
      c2 = fmaf(x[4 * q + 2], wv.z, c2); c3 = fmaf(x[4 * q + 3], wv.w, c3);
    }
    float s = (c0 + c1) + (c2 + c3);
    s += sb1[n];
    s = fmaf(s, ss1[n], sbe1[n]);
    a1[n] = fmaxf(s, 0.f);
  }

  // layer 2: 50 -> 30
  float a2[32]; a2[30] = 0.f; a2[31] = 0.f;
#pragma unroll
  for (int n = 0; n < 30; ++n) {
    const float4* wr = &sW2t[n * 13];
    float c0 = 0.f, c1 = 0.f, c2 = 0.f, c3 = 0.f;
#pragma unroll
    for (int q = 0; q < 13; ++q) {
      float4 wv = wr[q];
      c0 = fmaf(a1[4 * q + 0], wv.x, c0); c1 = fmaf(a1[4 * q + 1], wv.y, c1);
      c2 = fmaf(a1[4 * q + 2], wv.z, c2); c3 = fmaf(a1[4 * q + 3], wv.w, c3);
    }
    float s = (c0 + c1) + (c2 + c3);
    s += sb2[n];
    s = fmaf(s, ss2[n], sbe2[n]);
    a2[n] = fmaxf(s, 0.f);
  }

  // layer 3: 30 -> 20
  float a3[20];
#pragma unroll
  for (int n = 0; n < 20; ++n) {
    const float4* wr = &sW3t[n * 8];
    float c0 = 0.f, c1 = 0.f, c2 = 0.f, c3 = 0.f;
#pragma unroll
    for (int q = 0; q < 8; ++q) {
      float4 wv = wr[q];
      c0 = fmaf(a2[4 * q + 0], wv.x, c0); c1 = fmaf(a2[4 * q + 1], wv.y, c1);
      c2 = fmaf(a2[4 * q + 2], wv.z, c2); c3 = fmaf(a2[4 * q + 3], wv.w, c3);
    }
    float s = (c0 + c1) + (c2 + c3);
    s += sb3[n];
    s = fmaf(s, ss3[n], sbe3[n]);
    a3[n] = fmaxf(s, 0.f);
  }

  // layer 4: 20 -> 15 (no BN)
  float a4[16]; a4[15] = 0.f;
#pragma unroll
  for (int n = 0; n < 15; ++n) {
    const float4* wr = &sW4t[n * 5];
    float c0 = 0.f, c1 = 0.f, c2 = 0.f, c3 = 0.f;
#pragma unroll
    for (int q = 0; q < 5; ++q) {
      float4 wv = wr[q];
      c0 = fmaf(a3[4 * q + 0], wv.x, c0); c1 = fmaf(a3[4 * q + 1], wv.y, c1);
      c2 = fmaf(a3[4 * q + 2], wv.z, c2); c3 = fmaf(a3[4 * q + 3], wv.w, c3);
    }
    float s = (c0 + c1) + (c2 + c3);
    s += sb4[n];
    a4[n] = fmaxf(s, 0.f);
  }

  // layer 5: 15 -> 8, sigmoid
  float p[8];
#pragma unroll
  for (int n = 0; n < 8; ++n) {
    const float4* wr = &sW5t[n * 4];
    float c0 = 0.f, c1 = 0.f, c2 = 0.f, c3 = 0.f;
#pragma unroll
    for (int q = 0; q < 4; ++q) {
      float4 wv = wr[q];
      c0 = fmaf(a4[4 * q + 0], wv.x, c0); c1 = fmaf(a4[4 * q + 1], wv.y, c1);
      c2 = fmaf(a4[4 * q + 2], wv.z, c2); c3 = fmaf(a4[4 * q + 3], wv.w, c3);
    }
    float s = (c0 + c1) + (c2 + c3) + sb5[n];
    p[n] = 1.f / (1.f + expf(-s));
  }

  // bernoulli(1-p) via partitionable threefry + margin flag
  bool need = false;
  float prod = 1.f;
  float ch[8];
#pragma unroll
  for (int w = 0; w < 8; ++w) {
    unsigned j = 8u * (unsigned)b + (unsigned)w, o0, o1;
    tf2x32(0u, j, o0, o1);
    unsigned bits = o0 ^ o1;
    float u = __uint_as_float(0x3F800000u | (bits >> 9)) - 1.f;
    float thr = 1.f - p[w];
    bool choice = u < thr;
    need = need || (fabsf(u - thr) < P_MARGIN);
    ch[w] = choice ? 0.f : 1.f;
    prod *= choice ? thr : p[w];
  }
  if (need) {
    unsigned i = atomicAdd(&fixlist[0], 1u);
    if (i < fixcap) fixlist[1 + i] = (unsigned)b;
  }

  float4* oc = reinterpret_cast<float4*>(out_chosen) + (size_t)b * 2;
  oc[0] = make_float4(ch[0], ch[1], ch[2], ch[3]);
  oc[1] = make_float4(ch[4], ch[5], ch[6], ch[7]);
  out_logp[b] = logf(prod);
}

// ---------------- Pass 2: wave-cooperative fp64 repair ----------------
// One 64-lane wave per flagged row; lane n computes output neuron n.
// Weights read coalesced from global (L1/L2-hot), activations ping-pong in
// LDS. ~10 registers/lane, no spills, ~147-FMA critical path per row.
__global__ __launch_bounds__(64, 4)
void wtf_fix_kernel(const float* __restrict__ events,
                    const float* __restrict__ W1, const float* __restrict__ b1,
                    const float* __restrict__ g1, const float* __restrict__ be1,
                    const float* __restrict__ W2, const float* __restrict__ b2,
                    const float* __restrict__ g2, const float* __restrict__ be2,
                    const float* __restrict__ W3, const float* __restrict__ b3,
                    const float* __restrict__ g3, const float* __restrict__ be3,
                    const float* __restrict__ W4, const float* __restrict__ b4,
                    const float* __restrict__ W5, const float* __restrict__ b5,
                    float* __restrict__ out_chosen,
                    float* __restrict__ out_logp,
                    const unsigned* __restrict__ fixlist,
                    unsigned fixcap,
                    int B) {
  const unsigned raw = fixlist[0];
  const int cnt = (int)(raw < fixcap ? raw : fixcap);
  if ((int)blockIdx.x >= cnt) return;

  __shared__ double sA[64];  // activations ping
  __shared__ double sB[64];  // activations pong
  __shared__ double sF[8];   // flipped probs for log-prod

  const int t = threadIdx.x;
  const double denom = sqrt(1.0 + 1e-5);

  for (int idx = blockIdx.x; idx < cnt; idx += gridDim.x) {
    const int b = (int)fixlist[1 + idx];

    if (t < 32) sA[t] = (double)events[(size_t)b * 32 + t];
    __syncthreads();

    // layer 1: 32 -> 50 (+BN+ReLU). lane t = neuron t; W1[k*50+t] coalesced.
    double v = 0.0;
    if (t < 50) {
      for (int k = 0; k < 32; ++k) v = fma(sA[k], (double)W1[k * 50 + t], v);
      v += (double)b1[t];
      v = v * ((double)g1[t] / denom) + (double)be1[t];
      v = v > 0.0 ? v : 0.0;
    }
    __syncthreads();
    if (t < 50) sB[t] = v;
    __syncthreads();

    // layer 2: 50 -> 30
    v = 0.0;
    if (t < 30) {
      for (int k = 0; k < 50; ++k) v = fma(sB[k], (double)W2[k * 30 + t], v);
      v += (double)b2[t];
      v = v * ((double)g2[t] / denom) + (double)be2[t];
      v = v > 0.0 ? v : 0.0;
    }
    __syncthreads();
    if (t < 30) sA[t] = v;
    __syncthreads();

    // layer 3: 30 -> 20
    v = 0.0;
    if (t < 20) {
      for (int k = 0; k < 30; ++k) v = fma(sA[k], (double)W3[k * 20 + t], v);
      v += (double)b3[t];
      v = v * ((double)g3[t] / denom) + (double)be3[t];
      v = v > 0.0 ? v : 0.0;
    }
    __syncthreads();
    if (t < 20) sB[t] = v;
    __syncthreads();

    // layer 4: 20 -> 15 (no BN)
    v = 0.0;
    if (t < 15) {
      for (int k = 0; k < 20; ++k) v = fma(sB[k], (double)W4[k * 15 + t], v);
      v += (double)b4[t];
      v = v > 0.0 ? v : 0.0;
    }
    __syncthreads();
    if (t < 15) sA[t] = v;
    __syncthreads();

    // layer 5: 15 -> 8, sigmoid; then bernoulli + flipped prob
    if (t < 8) {
      v = 0.0;
      for (int k = 0; k < 15; ++k) v = fma(sA[k], (double)W5[k * 8 + t], v);
      v += (double)b5[t];
      double p = 1.0 / (1.0 + exp(-v));
      unsigned j = 8u * (unsigned)b + (unsigned)t, o0, o1;
      tf2x32(0u, j, o0, o1);
      unsigned bits = o0 ^ o1;
      float u = __uint_as_float(0x3F800000u | (bits >> 9)) - 1.f;
      double thr = 1.0 - p;
      bool choice = ((double)u < thr);
      out_chosen[(size_t)b * 8 + t] = choice ? 0.f : 1.f;
      sF[t] = choice ? thr : p;
    }
    __syncthreads();
    if (t == 0) {
      double prod = 1.0;
      for (int w = 0; w < 8; ++w) prod *= sF[w];
      out_logp[b] = (float)log(prod);
    }
    __syncthreads();
  }
}

extern "C" void kernel_launch(void* const* d_in, const int* in_sizes, int n_in,
                              void* d_out, int out_size, void* d_ws, size_t ws_size,
                              hipStream_t stream) {
  const float* events = (const float*)d_in[0];
  const float* W1  = (const float*)d_in[1];
  const float* b1  = (const float*)d_in[2];
  const float* g1  = (const float*)d_in[3];
  const float* be1 = (const float*)d_in[4];
  const float* W2  = (const float*)d_in[5];
  const float* b2  = (const float*)d_in[6];
  const float* g2  = (const float*)d_in[7];
  const float* be2 = (const float*)d_in[8];
  const float* W3  = (const float*)d_in[9];
  const float* b3  = (const float*)d_in[10];
  const float* g3  = (const float*)d_in[11];
  const float* be3 = (const float*)d_in[12];
  const float* W4  = (const float*)d_in[13];
  const float* b4  = (const float*)d_in[14];
  const float* W5  = (const float*)d_in[15];
  const float* b5  = (const float*)d_in[16];

  const int B = in_sizes[0] / 32;  // 524288
  float* out = (float*)d_out;
  float* out_chosen = out;                   // (B, 8)
  float* out_logp   = out + (size_t)B * 8;   // (B,)
  unsigned* fixlist = (unsigned*)d_ws;       // [0]=count, rows at [1+i]
  unsigned fixcap = (unsigned)(ws_size / sizeof(unsigned) - 1);
  if (fixcap > (unsigned)B) fixcap = (unsigned)B;

  hipMemsetAsync(d_ws, 0, sizeof(unsigned), stream);  // zero the counter

  const int blocks = (B + THREADS - 1) / THREADS;
  hipLaunchKernelGGL(wtf_fast_kernel, dim3(blocks), dim3(THREADS), 0, stream,
                     events, W1, b1, g1, be1, W2, b2, g2, be2,
                     W3, b3, g3, be3, W4, b4, W5, b5,
                     out_chosen, out_logp, fixlist, fixcap, B);
  hipLaunchKernelGGL(wtf_fix_kernel, dim3(1024), dim3(64), 0, stream,
                     events, W1, b1, g1, be1, W2, b2, g2, be2,
                     W3, b3, g3, be3, W4, b4, W5, b5,
                     out_chosen, out_logp, fixlist, fixcap, B);
}